// Round 6
// baseline (128.302 us; speedup 1.0000x reference)
//
#include <hip/hip_runtime.h>
#include <hip/hip_fp16.h>

// MinGRU single-pass fused pipeline, round 6.
// prologue: x,Wz,Wh fp32->bf16 + zero the aggregate mailbox (512 KB).
// gemm_scan_fused: XOR-swizzled async X staging (global_load_lds w=16,
//   BK=128 => 2 k-iters), W fragments loaded global->reg (L2-hot, no barrier),
//   bf16 MFMA 16x16x32, sigmoid epilogue -> LDS fp16 overlay, per-block
//   affine aggregate published as payload-in-atomic (LSB|=1), batched
//   decoupled lookback (8-wide), apply recurrence, nontemporal out stores.
// Co-residency: 1024 blocks, 36.1KB LDS + launch_bounds(256,4) => 4 blocks/CU
// all resident; lookback only waits on same-chain predecessors.

namespace {
constexpr int kB  = 8;
constexpr int kT  = 4096;
constexpr int kD  = 256;
constexpr int kH  = 256;
constexpr int kBT = kB * kT;

constexpr int TM  = 128;          // time rows per block
constexpr int TH  = 64;           // h cols per block (dual-W => 128 eff. N)
constexpr int BK  = 128;          // GEMM k tile (2 iters over K=256)
constexpr int kNT = kT / TM;      // 32 time-tiles per chain
constexpr int kNChain = kB * (kH / TH);   // 32 chains
constexpr int EPS = 66;           // epilogue LDS row stride (half)
} // namespace

typedef short s16x8 __attribute__((ext_vector_type(8)));
typedef short s16x4 __attribute__((ext_vector_type(4)));
typedef float f32x4 __attribute__((ext_vector_type(4)));

__device__ __forceinline__ short f2bf(float f) {
    union { float f; unsigned int u; } v; v.f = f;
    unsigned int r = v.u + 0x7fffu + ((v.u >> 16) & 1u);   // RNE
    return (short)(r >> 16);
}

__device__ __forceinline__ void load_lds16(const void* g, void* l) {
    __builtin_amdgcn_global_load_lds(
        (const __attribute__((address_space(1))) void*)g,
        (__attribute__((address_space(3))) void*)l, 16, 0, 0);
}

// ---------------------------------------------------------------------------
// Kernel 1: fp32 -> bf16 for x, Wz, Wh; zero the 512 KB aggregate mailbox.
// ---------------------------------------------------------------------------
__global__ __launch_bounds__(256)
void prologue(const float* __restrict__ x,
              const float* __restrict__ Wz,
              const float* __restrict__ Wh,
              unsigned short* __restrict__ xb,
              unsigned short* __restrict__ wzb,
              unsigned short* __restrict__ whb,
              float4* __restrict__ aggz)
{
    constexpr int X4 = kBT * kD / 4;          // 2,097,152
    constexpr int W4 = kH  * kD / 4;          // 16,384 each
    const int i = blockIdx.x * 256 + threadIdx.x;

    if (i >= X4 + 2 * W4) {                   // zero mailbox
        float4 z; z.x = 0.f; z.y = 0.f; z.z = 0.f; z.w = 0.f;
        aggz[i - (X4 + 2 * W4)] = z;
        return;
    }
    const float* src; unsigned short* dst; int j;
    if (i < X4)           { src = x;  dst = xb;  j = i; }
    else if (i < X4 + W4) { src = Wz; dst = wzb; j = i - X4; }
    else                  { src = Wh; dst = whb; j = i - X4 - W4; }
    const float4 v = ((const float4*)src)[j];
    s16x4 p;
    p[0] = f2bf(v.x); p[1] = f2bf(v.y); p[2] = f2bf(v.z); p[3] = f2bf(v.w);
    ((s16x4*)dst)[j] = p;
}

// ---------------------------------------------------------------------------
// Kernel 2: GEMM + sigmoid + block aggregate + lookback + apply + out.
// Grid: dim3(kNChain=32, kNT=32). 4 waves/block.
// ---------------------------------------------------------------------------
__global__ __launch_bounds__(256, 4)
void gemm_scan_fused(const unsigned short* __restrict__ xb,
                     const unsigned short* __restrict__ wzb,
                     const unsigned short* __restrict__ whb,
                     const float* __restrict__ bz,
                     const float* __restrict__ bh,
                     const float* __restrict__ h0,
                     unsigned long long* __restrict__ agg,  // [32 chains][32 t][64 h]
                     float* __restrict__ out)
{
    // LDS: Xs[128][128] bf16 (32KB, XOR-swizzled 16B blocks), overlaid after
    // the K loop by a_lds/b_lds [128][66] half; + sub_lds[4][64] float2
    // @33792 ; + hs_lds[64] float @35840.  Total 36096 B -> 4 blocks/CU.
    __shared__ __align__(16) unsigned char smem[36096];
    unsigned short* Xs = (unsigned short*)smem;      // [128 rows][128 k] swizzled
    __half* a_lds   = (__half*)smem;                 // [128][EPS]
    __half* b_lds   = a_lds + 128 * EPS;
    float2* sub_lds = (float2*)(smem + 33792);       // [4][64]
    float*  hs_lds  = (float*)(smem + 35840);        // [64]

    const int tid  = threadIdx.x;
    const int lane = tid & 63;
    const int wv   = tid >> 6;
    const int ln15 = lane & 15;
    const int quad = lane >> 4;
    const int wr0  = (wv & 1) * 64;
    const int wc0  = (wv >> 1) * 32;

    const int chain = blockIdx.x;            // 0..31
    const int t     = blockIdx.y;            // 0..31 (time-tile in chain)
    const int b     = chain >> 2;
    const int col0  = (chain & 3) * TH;
    const int row0  = b * kT + t * TM;       // global BT row of tile top

    // staging geometry: 32 segments of 1KB (4 rows x 256B); wave wv owns
    // segments wv*8..wv*8+7. lane covers row seg*4 + (lane>>4), 16B block
    // slot (lane&15); global block fetched = slot XOR (row & 15)  [swizzle].
    const int srow4 = lane >> 4;             // 0..3 row within segment
    const int slot  = lane & 15;             // 16B slot within row

    f32x4 accZ[4][2] = {};
    f32x4 accU[4][2] = {};

    for (int k0 = 0; k0 < kD; k0 += BK) {
        #pragma unroll
        for (int s = 0; s < 8; ++s) {
            const int seg = wv * 8 + s;                  // 0..31
            const int m   = seg * 4 + srow4;             // 0..127
            const int c   = slot ^ (m & 15);             // swizzled global block
            load_lds16(xb + (size_t)(row0 + m) * kD + k0 + c * 8,
                       Xs + seg * 512);
        }
        __syncthreads();   // drain DMA

        #pragma unroll
        for (int kk = 0; kk < BK; kk += 32) {
            const int cbase = kk >> 3;                   // 16B block of kk
            // A fragments from swizzled LDS: row r, block cbase+quad,
            // slot = (cbase+quad) ^ ln15  (r&15 == ln15).
            s16x8 af[4];
            #pragma unroll
            for (int mt = 0; mt < 4; ++mt) {
                const int r = wr0 + mt * 16 + ln15;
                af[mt] = *(const s16x8*)&Xs[r * 128 + (((cbase + quad) ^ ln15) << 3)];
            }
            // B fragments straight from global (L2-hot weights).
            s16x8 bzf[2], buf[2];
            #pragma unroll
            for (int nt = 0; nt < 2; ++nt) {
                const size_t wrow = (size_t)(col0 + wc0 + nt * 16 + ln15) * kD
                                  + k0 + kk + quad * 8;
                bzf[nt] = *(const s16x8*)(wzb + wrow);
                buf[nt] = *(const s16x8*)(whb + wrow);
            }
            #pragma unroll
            for (int mt = 0; mt < 4; ++mt) {
                #pragma unroll
                for (int nt = 0; nt < 2; ++nt) {
                    accZ[mt][nt] = __builtin_amdgcn_mfma_f32_16x16x32_bf16(
                        af[mt], bzf[nt], accZ[mt][nt], 0, 0, 0);
                    accU[mt][nt] = __builtin_amdgcn_mfma_f32_16x16x32_bf16(
                        af[mt], buf[nt], accU[mt][nt], 0, 0, 0);
                }
            }
        }
        __syncthreads();   // all waves done reading Xs before restage/overlay
    }

    // ---- epilogue: sigmoid; a/bb -> LDS fp16 (C/D: col=ln15, row=quad*4+r)
    #pragma unroll
    for (int nt = 0; nt < 2; ++nt) {
        const int col = col0 + wc0 + nt * 16 + ln15;
        const int lc  = wc0 + nt * 16 + ln15;
        const float bzv = bz[col];
        const float bhv = bh[col];
        #pragma unroll
        for (int mt = 0; mt < 4; ++mt) {
            const int rb = wr0 + mt * 16 + quad * 4;
            #pragma unroll
            for (int r = 0; r < 4; ++r) {
                const float z = accZ[mt][nt][r] + bzv;
                const float g = 1.0f / (1.0f + __expf(-z));
                const float u = accU[mt][nt][r] + bhv;
                a_lds[(rb + r) * EPS + lc] = __float2half_rn(1.0f - g);
                b_lds[(rb + r) * EPS + lc] = __float2half_rn(g * u);
            }
        }
    }
    __syncthreads();

    // ---- sub-chunk (32-row) affine summaries: thread (s,h)
    const int s = tid >> 6;
    const int h = tid & 63;
    {
        float A = 1.0f, Bv = 0.0f;
        #pragma unroll 8
        for (int r = s * 32; r < s * 32 + 32; ++r) {
            const float a  = __half2float(a_lds[r * EPS + h]);
            const float bb = __half2float(b_lds[r * EPS + h]);
            Bv = fmaf(a, Bv, bb);
            A *= a;
        }
        float2 o; o.x = A; o.y = Bv;
        sub_lds[s * 64 + h] = o;
    }
    __syncthreads();

    // ---- publish block aggregate + batched lookback (one lane per h)
    if (tid < 64) {
        float A = 1.0f, Bv = 0.0f;
        #pragma unroll
        for (int s2 = 0; s2 < 4; ++s2) {
            const float2 g = sub_lds[s2 * 64 + tid];
            Bv = fmaf(g.x, Bv, g.y);
            A *= g.x;
        }
        union { float2 f; unsigned long long u; } pk;
        pk.f.x = A; pk.f.y = Bv;
        pk.u |= 1ull;                         // never 0 => unambiguous ready flag
        __hip_atomic_store(&agg[(size_t)(chain * kNT + t) * 64 + tid], pk.u,
                           __ATOMIC_RELAXED, __HIP_MEMORY_SCOPE_AGENT);

        // lookback over predecessors 0..t-1, 8 at a time (independent loads,
        // one L2 latency per batch; fold strictly in order).
        float hs = h0[(size_t)b * kH + col0 + tid];
        for (int j0 = 0; j0 < t; j0 += 8) {
            const int nb = (t - j0 < 8) ? (t - j0) : 8;
            unsigned long long u[8];
            #pragma unroll
            for (int q = 0; q < 8; ++q)
                if (q < nb)
                    u[q] = __hip_atomic_load(
                        &agg[(size_t)(chain * kNT + j0 + q) * 64 + tid],
                        __ATOMIC_RELAXED, __HIP_MEMORY_SCOPE_AGENT);
            #pragma unroll
            for (int q = 0; q < 8; ++q) {
                if (q < nb) {
                    while (u[q] == 0ull)
                        u[q] = __hip_atomic_load(
                            &agg[(size_t)(chain * kNT + j0 + q) * 64 + tid],
                            __ATOMIC_RELAXED, __HIP_MEMORY_SCOPE_AGENT);
                    union { unsigned long long u; float2 f; } qk; qk.u = u[q];
                    hs = fmaf(qk.f.x, hs, qk.f.y);
                }
            }
        }
        hs_lds[tid] = hs;
    }
    __syncthreads();

    // ---- apply recurrence: thread (s,h) does its 32 rows, writes out
    {
        float hv = hs_lds[h];
        #pragma unroll
        for (int s2 = 0; s2 < s; ++s2) {
            const float2 g = sub_lds[s2 * 64 + h];
            hv = fmaf(g.x, hv, g.y);
        }
        #pragma unroll 8
        for (int r = 0; r < 32; ++r) {
            const int lr = s * 32 + r;
            const float a  = __half2float(a_lds[lr * EPS + h]);
            const float bb = __half2float(b_lds[lr * EPS + h]);
            hv = fmaf(a, hv, bb);
            __builtin_nontemporal_store(hv, &out[(size_t)(row0 + lr) * kH + col0 + h]);
        }
    }
}

extern "C" void kernel_launch(void* const* d_in, const int* in_sizes, int n_in,
                              void* d_out, int out_size, void* d_ws, size_t ws_size,
                              hipStream_t stream)
{
    const float* x  = (const float*)d_in[0];
    const float* h0 = (const float*)d_in[1];
    const float* Wz = (const float*)d_in[2];
    const float* bz = (const float*)d_in[3];
    const float* Wh = (const float*)d_in[4];
    const float* bh = (const float*)d_in[5];
    float* out = (float*)d_out;

    // Workspace: xb 16.78M | wzb/whb 131K each | agg 512K  => ~17.6 MB.
    unsigned char* ws = (unsigned char*)d_ws;
    unsigned short* xb  = (unsigned short*)ws;   ws += (size_t)kBT * kD * 2;
    unsigned short* wzb = (unsigned short*)ws;   ws += (size_t)kH * kD * 2;
    unsigned short* whb = (unsigned short*)ws;   ws += (size_t)kH * kD * 2;
    unsigned long long* agg = (unsigned long long*)ws;

    constexpr int PRO_ITEMS = kBT * kD / 4 + 2 * (kH * kD / 4)
                            + kNChain * kNT * TH * 8 / 16;   // 2,162,688
    prologue<<<PRO_ITEMS / 256, 256, 0, stream>>>(
        x, Wz, Wh, xb, wzb, whb, (float4*)agg);
    gemm_scan_fused<<<dim3(kNChain, kNT), 256, 0, stream>>>(
        xb, wzb, whb, bz, bh, h0, agg, out);
}

// Round 7
// 116.934 us; speedup vs baseline: 1.0972x; 1.0972x over previous
//
#include <hip/hip_runtime.h>
#include <hip/hip_fp16.h>

// MinGRU single-pass fused pipeline, round 7 = round 5 skeleton + XOR-swizzled
// LDS staging for BOTH X and W (kills the 16-way ds_read_b128 bank conflict
// that the unpadded global_load_lds layout forces) + batched lookback +
// nontemporal out stores (kept from round 6). W staging back through
// global_load_lds (round 6's W global->reg strided loads regressed).
// Swizzle scheme: row = 8 x 16B blocks; lane with LDS slot c fetches global
// block c ^ (row & 7); reader finds global block b of row r at slot b ^ (r&7).

namespace {
constexpr int kB  = 8;
constexpr int kT  = 4096;
constexpr int kD  = 256;
constexpr int kH  = 256;
constexpr int kBT = kB * kT;

constexpr int TM  = 128;          // time rows per block
constexpr int TH  = 64;           // h cols per block (dual-W => 128 eff. N)
constexpr int BK  = 64;           // GEMM k tile
constexpr int kNT = kT / TM;      // 32 time-tiles per chain
constexpr int kNChain = kB * (kH / TH);   // 32 chains
constexpr int EPS = 66;           // epilogue LDS row stride (half)
} // namespace

typedef short s16x8 __attribute__((ext_vector_type(8)));
typedef short s16x4 __attribute__((ext_vector_type(4)));
typedef float f32x4 __attribute__((ext_vector_type(4)));

__device__ __forceinline__ short f2bf(float f) {
    union { float f; unsigned int u; } v; v.f = f;
    unsigned int r = v.u + 0x7fffu + ((v.u >> 16) & 1u);   // RNE
    return (short)(r >> 16);
}

__device__ __forceinline__ void load_lds16(const void* g, void* l) {
    __builtin_amdgcn_global_load_lds(
        (const __attribute__((address_space(1))) void*)g,
        (__attribute__((address_space(3))) void*)l, 16, 0, 0);
}

// ---------------------------------------------------------------------------
// Kernel 1: fp32 -> bf16 for x, Wz, Wh; zero the 512 KB aggregate mailbox.
// ---------------------------------------------------------------------------
__global__ __launch_bounds__(256)
void prologue(const float* __restrict__ x,
              const float* __restrict__ Wz,
              const float* __restrict__ Wh,
              unsigned short* __restrict__ xb,
              unsigned short* __restrict__ wzb,
              unsigned short* __restrict__ whb,
              float4* __restrict__ aggz)
{
    constexpr int X4 = kBT * kD / 4;          // 2,097,152
    constexpr int W4 = kH  * kD / 4;          // 16,384 each
    const int i = blockIdx.x * 256 + threadIdx.x;

    if (i >= X4 + 2 * W4) {                   // zero mailbox
        float4 z; z.x = 0.f; z.y = 0.f; z.z = 0.f; z.w = 0.f;
        aggz[i - (X4 + 2 * W4)] = z;
        return;
    }
    const float* src; unsigned short* dst; int j;
    if (i < X4)           { src = x;  dst = xb;  j = i; }
    else if (i < X4 + W4) { src = Wz; dst = wzb; j = i - X4; }
    else                  { src = Wh; dst = whb; j = i - X4 - W4; }
    const float4 v = ((const float4*)src)[j];
    s16x4 p;
    p[0] = f2bf(v.x); p[1] = f2bf(v.y); p[2] = f2bf(v.z); p[3] = f2bf(v.w);
    ((s16x4*)dst)[j] = p;
}

// ---------------------------------------------------------------------------
// Kernel 2: GEMM + sigmoid + block aggregate + lookback + apply + out.
// Grid: dim3(kNChain=32, kNT=32). 4 waves/block, 4 blocks/CU (all resident).
// ---------------------------------------------------------------------------
__global__ __launch_bounds__(256, 4)
void gemm_scan_fused(const unsigned short* __restrict__ xb,
                     const unsigned short* __restrict__ wzb,
                     const unsigned short* __restrict__ whb,
                     const float* __restrict__ bz,
                     const float* __restrict__ bh,
                     const float* __restrict__ h0,
                     unsigned long long* __restrict__ agg,  // [32 chains][32 t][64 h]
                     float* __restrict__ out)
{
    // LDS: staging Xs[128][64] | Wzs[64][64] | Whs[64][64] ushort (32KB,
    // XOR-swizzled 16B blocks), overlaid after the K loop by a_lds/b_lds
    // [128][66] half; + sub_lds[4][64] float2 @33792 ; + hs_lds[64] @35840.
    __shared__ __align__(16) unsigned char smem[36096];
    unsigned short* Xs  = (unsigned short*)smem;
    unsigned short* Wzs = Xs  + 128 * 64;
    unsigned short* Whs = Wzs + 64 * 64;
    __half* a_lds   = (__half*)smem;                 // [128][EPS]
    __half* b_lds   = a_lds + 128 * EPS;
    float2* sub_lds = (float2*)(smem + 33792);       // [4][64]
    float*  hs_lds  = (float*)(smem + 35840);        // [64]

    const int tid  = threadIdx.x;
    const int lane = tid & 63;
    const int wv   = tid >> 6;
    const int ln15 = lane & 15;
    const int quad = lane >> 4;
    const int wr0  = (wv & 1) * 64;
    const int wc0  = (wv >> 1) * 32;

    const int chain = blockIdx.x;            // 0..31
    const int t     = blockIdx.y;            // 0..31 (time-tile in chain)
    const int b     = chain >> 2;
    const int col0  = (chain & 3) * TH;
    const int row0  = b * kT + t * TM;       // global BT row of tile top

    // staging geometry: segments of 8 rows x 128B; lane covers row
    // seg*8 + (lane>>3), LDS 16B slot (lane&7); fetched global block =
    // slot ^ (srow) since (abs row)&7 == srow.
    const int srow = lane >> 3;              // 0..7
    const int swslot = (lane & 7) ^ srow;    // swizzled global 16B block

    f32x4 accZ[4][2] = {};
    f32x4 accU[4][2] = {};

    for (int k0 = 0; k0 < kD; k0 += BK) {
        #pragma unroll
        for (int s = 0; s < 4; ++s) {
            const int seg = wv * 4 + s;                  // 0..15
            const int m = seg * 8 + srow;                // 0..127
            load_lds16(xb + (size_t)(row0 + m) * kD + k0 + swslot * 8,
                       Xs + seg * 512);
        }
        #pragma unroll
        for (int s = 0; s < 2; ++s) {
            const int seg = wv * 2 + s;                  // 0..7
            const int m = seg * 8 + srow;                // 0..63
            load_lds16(wzb + (size_t)(col0 + m) * kD + k0 + swslot * 8,
                       Wzs + seg * 512);
            load_lds16(whb + (size_t)(col0 + m) * kD + k0 + swslot * 8,
                       Whs + seg * 512);
        }
        __syncthreads();   // drain DMA

        #pragma unroll
        for (int kk = 0; kk < BK; kk += 32) {
            const int bblk = (kk >> 3) + quad;           // global 16B block 0..7
            s16x8 af[4], bzf[2], buf[2];
            #pragma unroll
            for (int mt = 0; mt < 4; ++mt) {
                const int r = wr0 + mt * 16 + ln15;
                af[mt] = *(const s16x8*)&Xs[r * 64 + ((bblk ^ (r & 7)) << 3)];
            }
            #pragma unroll
            for (int nt = 0; nt < 2; ++nt) {
                const int rw = wc0 + nt * 16 + ln15;
                const int so = (bblk ^ (rw & 7)) << 3;
                bzf[nt] = *(const s16x8*)&Wzs[rw * 64 + so];
                buf[nt] = *(const s16x8*)&Whs[rw * 64 + so];
            }
            #pragma unroll
            for (int mt = 0; mt < 4; ++mt) {
                #pragma unroll
                for (int nt = 0; nt < 2; ++nt) {
                    accZ[mt][nt] = __builtin_amdgcn_mfma_f32_16x16x32_bf16(
                        af[mt], bzf[nt], accZ[mt][nt], 0, 0, 0);
                    accU[mt][nt] = __builtin_amdgcn_mfma_f32_16x16x32_bf16(
                        af[mt], buf[nt], accU[mt][nt], 0, 0, 0);
                }
            }
        }
        __syncthreads();   // all waves done with staging LDS
    }

    // ---- epilogue: sigmoid; a/bb -> LDS fp16 (C/D: col=ln15, row=quad*4+r)
    #pragma unroll
    for (int nt = 0; nt < 2; ++nt) {
        const int col = col0 + wc0 + nt * 16 + ln15;
        const int lc  = wc0 + nt * 16 + ln15;
        const float bzv = bz[col];
        const float bhv = bh[col];
        #pragma unroll
        for (int mt = 0; mt < 4; ++mt) {
            const int rb = wr0 + mt * 16 + quad * 4;
            #pragma unroll
            for (int r = 0; r < 4; ++r) {
                const float z = accZ[mt][nt][r] + bzv;
                const float g = 1.0f / (1.0f + __expf(-z));
                const float u = accU[mt][nt][r] + bhv;
                a_lds[(rb + r) * EPS + lc] = __float2half_rn(1.0f - g);
                b_lds[(rb + r) * EPS + lc] = __float2half_rn(g * u);
            }
        }
    }
    __syncthreads();

    // ---- sub-chunk (32-row) affine summaries: thread (s,h)
    const int s = tid >> 6;
    const int h = tid & 63;
    {
        float A = 1.0f, Bv = 0.0f;
        #pragma unroll 8
        for (int r = s * 32; r < s * 32 + 32; ++r) {
            const float a  = __half2float(a_lds[r * EPS + h]);
            const float bb = __half2float(b_lds[r * EPS + h]);
            Bv = fmaf(a, Bv, bb);
            A *= a;
        }
        float2 o; o.x = A; o.y = Bv;
        sub_lds[s * 64 + h] = o;
    }
    __syncthreads();

    // ---- publish block aggregate + batched lookback (one lane per h)
    if (tid < 64) {
        float A = 1.0f, Bv = 0.0f;
        #pragma unroll
        for (int s2 = 0; s2 < 4; ++s2) {
            const float2 g = sub_lds[s2 * 64 + tid];
            Bv = fmaf(g.x, Bv, g.y);
            A *= g.x;
        }
        union { float2 f; unsigned long long u; } pk;
        pk.f.x = A; pk.f.y = Bv;
        pk.u |= 1ull;                         // never 0 => unambiguous ready flag
        __hip_atomic_store(&agg[(size_t)(chain * kNT + t) * 64 + tid], pk.u,
                           __ATOMIC_RELAXED, __HIP_MEMORY_SCOPE_AGENT);

        // lookback over predecessors 0..t-1, 8 at a time (independent loads,
        // one L2/L3 latency per batch; fold strictly in order).
        float hs = h0[(size_t)b * kH + col0 + tid];
        for (int j0 = 0; j0 < t; j0 += 8) {
            const int nb = (t - j0 < 8) ? (t - j0) : 8;
            unsigned long long u[8];
            #pragma unroll
            for (int q = 0; q < 8; ++q)
                if (q < nb)
                    u[q] = __hip_atomic_load(
                        &agg[(size_t)(chain * kNT + j0 + q) * 64 + tid],
                        __ATOMIC_RELAXED, __HIP_MEMORY_SCOPE_AGENT);
            #pragma unroll
            for (int q = 0; q < 8; ++q) {
                if (q < nb) {
                    while (u[q] == 0ull)
                        u[q] = __hip_atomic_load(
                            &agg[(size_t)(chain * kNT + j0 + q) * 64 + tid],
                            __ATOMIC_RELAXED, __HIP_MEMORY_SCOPE_AGENT);
                    union { unsigned long long u; float2 f; } qk; qk.u = u[q];
                    hs = fmaf(qk.f.x, hs, qk.f.y);
                }
            }
        }
        hs_lds[tid] = hs;
    }
    __syncthreads();

    // ---- apply recurrence: thread (s,h) does its 32 rows, writes out
    {
        float hv = hs_lds[h];
        #pragma unroll
        for (int s2 = 0; s2 < s; ++s2) {
            const float2 g = sub_lds[s2 * 64 + h];
            hv = fmaf(g.x, hv, g.y);
        }
        #pragma unroll 8
        for (int r = 0; r < 32; ++r) {
            const int lr = s * 32 + r;
            const float a  = __half2float(a_lds[lr * EPS + h]);
            const float bb = __half2float(b_lds[lr * EPS + h]);
            hv = fmaf(a, hv, bb);
            __builtin_nontemporal_store(hv, &out[(size_t)(row0 + lr) * kH + col0 + h]);
        }
    }
}

extern "C" void kernel_launch(void* const* d_in, const int* in_sizes, int n_in,
                              void* d_out, int out_size, void* d_ws, size_t ws_size,
                              hipStream_t stream)
{
    const float* x  = (const float*)d_in[0];
    const float* h0 = (const float*)d_in[1];
    const float* Wz = (const float*)d_in[2];
    const float* bz = (const float*)d_in[3];
    const float* Wh = (const float*)d_in[4];
    const float* bh = (const float*)d_in[5];
    float* out = (float*)d_out;

    // Workspace: xb 16.78M | wzb/whb 131K each | agg 512K  => ~17.6 MB.
    unsigned char* ws = (unsigned char*)d_ws;
    unsigned short* xb  = (unsigned short*)ws;   ws += (size_t)kBT * kD * 2;
    unsigned short* wzb = (unsigned short*)ws;   ws += (size_t)kH * kD * 2;
    unsigned short* whb = (unsigned short*)ws;   ws += (size_t)kH * kD * 2;
    unsigned long long* agg = (unsigned long long*)ws;

    constexpr int PRO_ITEMS = kBT * kD / 4 + 2 * (kH * kD / 4)
                            + kNChain * kNT * TH * 8 / 16;   // 2,162,688
    prologue<<<PRO_ITEMS / 256, 256, 0, stream>>>(
        x, Wz, Wh, xb, wzb, whb, (float4*)agg);
    gemm_scan_fused<<<dim3(kNChain, kNT), 256, 0, stream>>>(
        xb, wzb, whb, bz, bh, h0, agg, out);
}